// Round 1
// baseline (116.955 us; speedup 1.0000x reference)
//
#include <hip/hip_runtime.h>

namespace {
constexpr int CH = 128, HH = 56, WW = 56;

__global__ __launch_bounds__(256, 4) void fused_conv_kernel(
    const float* __restrict__ x,
    const float* __restrict__ w0,
    const float* __restrict__ w1,
    float* __restrict__ out)
{
    __shared__ float xs[CH * WW];        // [ch][l]
    __shared__ float t4s[4][2][57];      // [i][m][l] (pad to 57 to decouple rows)
    __shared__ float w0s[2 * 3 * 3 * 32];
    __shared__ float w1s[64 * 4];

    const int tid = threadIdx.x;
    const int b   = blockIdx.x / HH;
    const int h   = blockIdx.x % HH;

    // stage weights (tiny)
    for (int t = tid; t < 576; t += 256) w0s[t] = w0[t];
    if (tid < 256) w1s[tid] = w1[tid];

    const size_t chan_stride = (size_t)HH * WW;
    const float* xrow = x + ((size_t)b * CH * HH + h) * WW;   // x[b][0][h][0]

    // load x[b, :, h, :] : 128 rows x 56 floats = 1792 float4 (rows 16B-aligned)
    #pragma unroll
    for (int it = 0; it < 7; ++it) {
        int t  = it * 256 + tid;          // 0..1791
        int ch = t / 14;
        int q  = t - ch * 14;
        float4 v = *reinterpret_cast<const float4*>(xrow + (size_t)ch * chan_stride + q * 4);
        *reinterpret_cast<float4*>(&xs[ch * WW + q * 4]) = v;
    }
    __syncthreads();

    // stage 1: t4s[i][m][l] = sum_j xs[(2j+m)*56 + l] * w1[j,i]
    for (int idx = tid; idx < 448; idx += 256) {
        int m = idx & 1;
        int l = (idx >> 1) % 56;
        int i = idx / 112;
        float acc = 0.f;
        #pragma unroll
        for (int j = 0; j < 64; ++j)
            acc = fmaf(xs[(2 * j + m) * WW + l], w1s[j * 4 + i], acc);
        t4s[i][m][l] = acc;
    }
    __syncthreads();

    // stage 2: pre[b,h,w,j,i] = sum_{m,kB,kA} t4[m, w+kA+kB-2, i] * w0[m,kB,kA,j]
    // with kB-validity (w+kB-1 in [0,56)) handled as boundary fixups.
    const int h_out = (h + 1) % HH;                   // roll(+1) along H
    float* orow = out + ((size_t)b * CH * HH + h_out) * WW;
    #pragma unroll
    for (int it = 0; it < 7; ++it) {
        int t  = it * 256 + tid;          // 0..1791
        int c  = t / 14;                  // output channel = j*4+i
        int q  = t - c * 14;
        int l0 = q * 4;                   // 4 consecutive w per thread
        int j  = c >> 2;
        int i  = c & 3;

        // vals[m][d] holds t4[i][m][l0-2+d], zero-filled out of range (d=0..7)
        float vals[2][8];
        #pragma unroll
        for (int m = 0; m < 2; ++m)
            #pragma unroll
            for (int d = 0; d < 8; ++d) {
                int lsrc = l0 - 2 + d;
                vals[m][d] = (lsrc >= 0 && lsrc < WW) ? t4s[i][m][lsrc] : 0.f;
            }

        float acc0 = 0.f, acc1 = 0.f, acc2 = 0.f, acc3 = 0.f;
        #pragma unroll
        for (int m = 0; m < 2; ++m)
            #pragma unroll
            for (int kB = 0; kB < 3; ++kB)
                #pragma unroll
                for (int kA = 0; kA < 3; ++kA) {
                    float wv = w0s[((m * 3 + kB) * 3 + kA) * 32 + j];
                    int dd = kA + kB;
                    acc0 = fmaf(vals[m][dd],     wv, acc0);
                    acc1 = fmaf(vals[m][dd + 1], wv, acc1);
                    acc2 = fmaf(vals[m][dd + 2], wv, acc2);
                    acc3 = fmaf(vals[m][dd + 3], wv, acc3);
                }

        // boundary fixups: kB=0 invalid at w=0; kB=2 invalid at w=55
        if (l0 == 0) {
            #pragma unroll
            for (int m = 0; m < 2; ++m)
                acc0 -= t4s[i][m][0] * w0s[((m * 3 + 0) * 3 + 2) * 32 + j];
        }
        if (l0 == 52) {
            #pragma unroll
            for (int m = 0; m < 2; ++m)
                acc3 -= t4s[i][m][55] * w0s[((m * 3 + 2) * 3 + 0) * 32 + j];
        }

        float4 res = make_float4(acc0, acc1, acc2, acc3);
        *reinterpret_cast<float4*>(orow + (size_t)c * chan_stride + l0) = res;
    }
}
} // namespace

extern "C" void kernel_launch(void* const* d_in, const int* in_sizes, int n_in,
                              void* d_out, int out_size, void* d_ws, size_t ws_size,
                              hipStream_t stream) {
    const float* x  = (const float*)d_in[0];
    const float* w0 = (const float*)d_in[1];
    const float* w1 = (const float*)d_in[2];
    float* out = (float*)d_out;
    fused_conv_kernel<<<dim3(128 * 56), dim3(256), 0, stream>>>(x, w0, w1, out);
}